// Round 1
// baseline (162.323 us; speedup 1.0000x reference)
//
#include <hip/hip_runtime.h>

// HDR+ align: 4-level gaussian pyramid + tile block matching + subpixel refine.
// Constants from reference: T=16, SR=4, PADD=1, SS=11, SSC=9, WIN=26, SW=0.1, GR=2.

#define TSZ 16
#define SS 11
#define SSC 9
#define WIN 26
#define NB 4   // batch

// Composite 1D tap of (gaussian blur, normalized, sigma=1, radius 2) followed by avg-pool-2:
// h[u] = 0.5*(gn[u] + gn[u-1]) for u in 0..5, gn out-of-range -> 0.
__device__ __constant__ float c_h[6] = {
    0.027244342f, 0.149345013f, 0.323410645f,
    0.323410645f, 0.149345013f, 0.027244342f
};

// Fused blur(zero-pad) + 2x2 avg-pool downsample. z in [0,8): z<4 -> src imgs, else dst imgs.
__global__ void pyr_down_kernel(const float* __restrict__ inS, const float* __restrict__ inD,
                                float* __restrict__ outS, float* __restrict__ outD,
                                int Hi, int Wi) {
    int Ho = Hi >> 1, Wo = Wi >> 1;
    int x = blockIdx.x * 16 + threadIdx.x;
    int y = blockIdx.y * 16 + threadIdx.y;
    int z = blockIdx.z;
    if (x >= Wo || y >= Ho) return;
    const float* in  = (z < 4) ? (inS  + (size_t)z * Hi * Wi) : (inD  + (size_t)(z - 4) * Hi * Wi);
    float*       out = (z < 4) ? (outS + (size_t)z * Ho * Wo) : (outD + (size_t)(z - 4) * Ho * Wo);
    int ybase = 2 * y - 2, xbase = 2 * x - 2;
    float acc = 0.0f;
    #pragma unroll
    for (int u = 0; u < 6; ++u) {
        int yy = ybase + u;
        if (yy < 0 || yy >= Hi) continue;   // zero padding
        float rowacc = 0.0f;
        #pragma unroll
        for (int v = 0; v < 6; ++v) {
            int xx = xbase + v;
            if (xx < 0 || xx >= Wi) continue;
            rowacc = fmaf(c_h[v], in[yy * Wi + xx], rowacc);
        }
        acc = fmaf(c_h[u], rowacc, acc);
    }
    out[y * Wo + x] = acc;
}

// One block-matching step for one pyramid level. One block per tile, 128 threads.
// prevOff == nullptr at coarsest level (init offset zero). outMinDist non-null only at level 0.
__global__ void step_kernel(const float* __restrict__ srcLvl, const float* __restrict__ dstLvl,
                            const float* __restrict__ prevOff, float* __restrict__ outOff,
                            float* __restrict__ outMinDist,
                            int H, int W, int nth, int ntw, int prev_nth, int prev_ntw) {
    __shared__ float win[WIN * WIN];     // 26x26 dst window
    __shared__ float stile[TSZ * TSZ];   // 16x16 src tile
    __shared__ float dist[SS * SS];      // 11x11 dist_full
    __shared__ float initf[2];
    __shared__ int   ioff[2];

    const int tx = blockIdx.x, ty = blockIdx.y, b = blockIdx.z;
    const int t = threadIdx.x;

    if (t == 0) {
        float dyf = 0.0f, dxf = 0.0f;
        if (prevOff != nullptr) {
            int pty = ty >> 1, ptx = tx >> 1;
            const float* p = prevOff + ((size_t)(b * prev_nth + pty) * prev_ntw + ptx) * 2;
            float o0 = 2.0f * p[0], o1 = 2.0f * p[1];
            float iy = (float)(ty * TSZ), ix = (float)(tx * TSZ);
            // _inherit: clip(off+i, 0, H-T) - i, then round (half-to-even like jnp.round)
            dyf = rintf(fminf(fmaxf(o0 + iy, 0.0f), (float)(H - TSZ)) - iy);
            dxf = rintf(fminf(fmaxf(o1 + ix, 0.0f), (float)(W - TSZ)) - ix);
        }
        initf[0] = dyf; initf[1] = dxf;
        ioff[0] = (int)dyf; ioff[1] = (int)dxf;
    }
    __syncthreads();

    const float* simg = srcLvl + (size_t)b * H * W;
    const float* dimg = dstLvl + (size_t)b * H * W;
    const int y0 = ty * TSZ + ioff[0] - (SS / 2);   // - (SR+PADD) = -5
    const int x0 = tx * TSZ + ioff[1] - (SS / 2);

    for (int idx = t; idx < WIN * WIN; idx += 128) {
        int r = idx / WIN, c = idx - r * WIN;
        int gy = min(max(y0 + r, 0), H - 1);
        int gx = min(max(x0 + c, 0), W - 1);
        win[idx] = dimg[gy * W + gx];
    }
    for (int idx = t; idx < TSZ * TSZ; idx += 128) {
        int i = idx >> 4, j = idx & 15;
        stile[idx] = simg[(ty * TSZ + i) * W + tx * TSZ + j];
    }
    __syncthreads();

    if (t < SS * SS) {
        int dy = t / SS, dx = t - dy * SS;
        float ssd = 0.0f;
        const float* wbase = &win[dy * WIN + dx];
        #pragma unroll 4
        for (int i = 0; i < TSZ; ++i) {
            const float* wr = wbase + i * WIN;
            const float* sr = &stile[i * TSZ];
            #pragma unroll
            for (int j = 0; j < TSZ; ++j) {
                float d = wr[j] - sr[j];
                ssd = fmaf(d, d, ssd);
            }
        }
        float ay = (float)(dy - 5) * (1.0f / 11.0f);
        float ax = (float)(dx - 5) * (1.0f / 11.0f);
        dist[t] = ssd * (1.0f / 256.0f) + 0.1f * (ay * ay + ax * ax);
    }
    __syncthreads();

    if (t == 0) {
        // argmin over central 9x9, row-major, first occurrence (matches jnp.argmin)
        float best = dist[1 * SS + 1];
        int bk = 0;
        for (int k = 1; k < SSC * SSC; ++k) {
            int py = k / SSC, px = k - (k / SSC) * SSC;
            float v = dist[(py + 1) * SS + (px + 1)];
            if (v < best) { best = v; bk = k; }
        }
        int py = bk / SSC, px = bk - py * SSC;
        // 3x3 neighborhood of peak in full 11x11 coords: rows py..py+2, cols px..px+2
        float y00 = dist[(py + 0) * SS + (px + 0)], y01 = dist[(py + 0) * SS + (px + 1)], y02 = dist[(py + 0) * SS + (px + 2)];
        float y10 = dist[(py + 1) * SS + (px + 0)], y11 = dist[(py + 1) * SS + (px + 1)], y12 = dist[(py + 1) * SS + (px + 2)];
        float y20 = dist[(py + 2) * SS + (px + 0)], y21 = dist[(py + 2) * SS + (px + 1)], y22 = dist[(py + 2) * SS + (px + 2)];

        float a11 = (y00 - 2.0f * y01 + y02 + 2.0f * y10 - 4.0f * y11 + 2.0f * y12 + y20 - 2.0f * y21 + y22) * 0.25f;
        a11 = fmaxf(a11, 0.0f);
        float a22 = (y00 + 2.0f * y01 + y02 - 2.0f * y10 - 4.0f * y11 - 2.0f * y12 + y20 + 2.0f * y21 + y22) * 0.25f;
        a22 = fmaxf(a22, 0.0f);
        float a12 = (y00 - y02 - y20 + y22) * 0.25f;
        float b1  = (-y00 + y02 - 2.0f * y10 + 2.0f * y12 - y20 + y22) * 0.125f;
        float b2  = (-y00 - 2.0f * y01 - y02 + y20 + 2.0f * y21 + y22) * 0.125f;

        float det  = a11 * a22 - a12 * a12;
        float a12z = (det < 0.0f) ? 0.0f : a12;
        float mu_x = -(a22 * b1 - a12z * b2) / det;   // inf/nan when det==0 -> filtered below
        float mu_y = -(a11 * b2 - a12z * b1) / det;
        float mu_len = sqrtf(mu_x * mu_x + mu_y * mu_y);
        float addx = (mu_len < 1.0f) ? mu_x : 0.0f;   // NaN compares false, matching jnp.where
        float addy = (mu_len < 1.0f) ? mu_y : 0.0f;

        float offy = initf[0] + (float)(py - 4) + addy;
        float offx = initf[1] + (float)(px - 4) + addx;
        float* o = outOff + ((size_t)(b * nth + ty) * ntw + tx) * 2;
        o[0] = offy;
        o[1] = offx;
        if (outMinDist != nullptr) outMinDist[(size_t)(b * nth + ty) * ntw + tx] = best;
    }
}

// Expand (4,32,32,2) offsets and (4,32,32) min_dist to pixel resolution, concat-flat.
__global__ void expand_kernel(const float* __restrict__ off, const float* __restrict__ mind,
                              float* __restrict__ out) {
    int idx = blockIdx.x * 256 + threadIdx.x;   // over 4*512*512
    const int NPIX = NB * 512 * 512;
    if (idx >= NPIX) return;
    int x = idx & 511;
    int y = (idx >> 9) & 511;
    int b = idx >> 18;
    int ti = (b * 32 + (y >> 4)) * 32 + (x >> 4);
    out[(size_t)idx * 2 + 0] = off[ti * 2 + 0];
    out[(size_t)idx * 2 + 1] = off[ti * 2 + 1];
    out[(size_t)NPIX * 2 + idx] = mind[ti];
}

extern "C" void kernel_launch(void* const* d_in, const int* in_sizes, int n_in,
                              void* d_out, int out_size, void* d_ws, size_t ws_size,
                              hipStream_t stream) {
    const float* src = (const float*)d_in[0];   // (4,1,512,512)
    const float* dst = (const float*)d_in[1];   // (4,1,512,512)
    float* out = (float*)d_out;                  // 4*512*512*2 offsets ++ 4*512*512 dist
    float* ws  = (float*)d_ws;

    // Workspace layout (floats):
    float* off3  = ws;               // 4*4*4*2    = 128
    float* off2  = ws + 128;         // 4*8*8*2    = 512
    float* off1  = ws + 640;         // 4*16*16*2  = 2048
    float* off0  = ws + 2688;        // 4*32*32*2  = 8192
    float* mind0 = ws + 10880;       // 4*32*32    = 4096
    float* sL1 = ws + 16384;         // 4*256*256  = 262144
    float* sL2 = sL1 + 262144;       // 4*128*128  = 65536
    float* sL3 = sL2 + 65536;        // 4*64*64    = 16384
    float* dL1 = sL3 + 16384;
    float* dL2 = dL1 + 262144;
    float* dL3 = dL2 + 65536;

    dim3 blk(16, 16);
    hipLaunchKernelGGL(pyr_down_kernel, dim3(16, 16, 8), blk, 0, stream, src, dst, sL1, dL1, 512, 512);
    hipLaunchKernelGGL(pyr_down_kernel, dim3(8, 8, 8),   blk, 0, stream, sL1, dL1, sL2, dL2, 256, 256);
    hipLaunchKernelGGL(pyr_down_kernel, dim3(4, 4, 8),   blk, 0, stream, sL2, dL2, sL3, dL3, 128, 128);

    hipLaunchKernelGGL(step_kernel, dim3(4, 4, NB),   dim3(128), 0, stream, sL3, dL3, nullptr, off3, nullptr, 64, 64, 4, 4, 0, 0);
    hipLaunchKernelGGL(step_kernel, dim3(8, 8, NB),   dim3(128), 0, stream, sL2, dL2, off3, off2, nullptr, 128, 128, 8, 8, 4, 4);
    hipLaunchKernelGGL(step_kernel, dim3(16, 16, NB), dim3(128), 0, stream, sL1, dL1, off2, off1, nullptr, 256, 256, 16, 16, 8, 8);
    hipLaunchKernelGGL(step_kernel, dim3(32, 32, NB), dim3(128), 0, stream, src, dst, off1, off0, mind0, 512, 512, 32, 32, 16, 16);

    hipLaunchKernelGGL(expand_kernel, dim3((NB * 512 * 512 + 255) / 256), dim3(256), 0, stream, off0, mind0, out);
}